// Round 1
// baseline (318.912 us; speedup 1.0000x reference)
//
#include <hip/hip_runtime.h>
#include <stdint.h>

typedef unsigned short u16;
typedef __bf16 bf16x8 __attribute__((ext_vector_type(8)));
typedef float f32x4 __attribute__((ext_vector_type(4)));

__device__ __forceinline__ u16 f2bf(float f) {
  union { float f; uint32_t u; } x; x.f = f;
  uint32_t u = x.u;
  u += 0x7fffu + ((u >> 16) & 1u);   // round-to-nearest-even
  return (u16)(u >> 16);
}

__device__ __forceinline__ void async_load16(const u16* g, u16* l) {
  __builtin_amdgcn_global_load_lds(
      (const __attribute__((address_space(1))) void*)g,
      (__attribute__((address_space(3))) void*)l,
      16, 0, 0);
}

// ---------------- conversions ----------------
__global__ __launch_bounds__(256) void sigmoid_k(const float* __restrict__ in,
                                                 float* __restrict__ out, int n) {
  int i = blockIdx.x * 256 + threadIdx.x;
  if (i < n) out[i] = 1.0f / (1.0f + expf(-in[i]));
}

__global__ __launch_bounds__(256) void cvt_f32_bf16(const float* __restrict__ in,
                                                    u16* __restrict__ out, int n) {
  int i = (blockIdx.x * 256 + threadIdx.x) * 4;
  if (i < n) {
    float4 v = *(const float4*)(in + i);
    ushort4 o;
    o.x = f2bf(v.x); o.y = f2bf(v.y); o.z = f2bf(v.z); o.w = f2bf(v.w);
    *(ushort4*)(out + i) = o;
  }
}

// ---------------- GEMM: C = A (MxK, bf16) * B^T (NxK, bf16) + bias, opt ReLU ----------------
// 128x128 tile, BK=32, 4 waves (2x2), each wave 64x64 via 4x4 mfma_f32_16x16x32_bf16.
template <int RELU>
__global__ __launch_bounds__(256) void gemm_bt(const u16* __restrict__ A,
                                               const u16* __restrict__ B,
                                               const float* __restrict__ bias,
                                               float* __restrict__ C,
                                               int M, int N, int K) {
  __shared__ u16 As[128 * 32];
  __shared__ u16 Bs[128 * 32];

  const int tid  = threadIdx.x;
  const int lane = tid & 63;

  const int tile_m = blockIdx.y * 128;
  const int tile_n = blockIdx.x * 128;

  const int wm = ((tid >> 7) & 1) * 64;  // wave row
  const int wn = ((tid >> 6) & 1) * 64;  // wave col

  // staging: thread tid loads 8 bf16 (16B) from row tid/4, col (tid%4)*8 (+64 rows on 2nd issue)
  const int srow = tid >> 2;
  const int scol = (tid & 3) << 3;
  u16* ldsA = &As[(tid >> 6) << 9];  // wave-uniform base: wave*512 elements
  u16* ldsB = &Bs[(tid >> 6) << 9];

  const u16* gA = A + (size_t)(tile_m + srow) * K + scol;
  const u16* gB = B + (size_t)(tile_n + srow) * K + scol;

  f32x4 acc[4][4];
#pragma unroll
  for (int i = 0; i < 4; i++)
#pragma unroll
    for (int j = 0; j < 4; j++) acc[i][j] = (f32x4){0.f, 0.f, 0.f, 0.f};

  const int lrow = lane & 15;
  const int kq   = (lane >> 4) << 3;

  for (int k0 = 0; k0 < K; k0 += 32) {
    __syncthreads();
    async_load16(gA + k0, ldsA);
    async_load16(gA + 64 * (size_t)K + k0, ldsA + 2048);
    async_load16(gB + k0, ldsB);
    async_load16(gB + 64 * (size_t)K + k0, ldsB + 2048);
    __syncthreads();  // drains vmcnt: LDS tiles complete

    bf16x8 a[4], b[4];
#pragma unroll
    for (int i = 0; i < 4; i++)
      a[i] = *(const bf16x8*)&As[(wm + i * 16 + lrow) * 32 + kq];
#pragma unroll
    for (int j = 0; j < 4; j++)
      b[j] = *(const bf16x8*)&Bs[(wn + j * 16 + lrow) * 32 + kq];
#pragma unroll
    for (int i = 0; i < 4; i++)
#pragma unroll
      for (int j = 0; j < 4; j++)
        acc[i][j] = __builtin_amdgcn_mfma_f32_16x16x32_bf16(a[i], b[j], acc[i][j], 0, 0, 0);
  }

  // C/D layout: col = lane&15, row = (lane>>4)*4 + r  [measured m89/m91]
  const int crow = (lane >> 4) << 2;
  const int ccol = lane & 15;
#pragma unroll
  for (int i = 0; i < 4; i++) {
#pragma unroll
    for (int j = 0; j < 4; j++) {
      const int gm = tile_m + wm + i * 16 + crow;
      const int gn = tile_n + wn + j * 16 + ccol;
      const float bv = bias[gn];
#pragma unroll
      for (int r = 0; r < 4; r++) {
        float v = acc[i][j][r] + bv;
        if (RELU) v = fmaxf(v, 0.f);
        C[(size_t)(gm + r) * N + gn] = v;
      }
    }
  }
}

// ---------------- scan: m_t = beta*m_{t-1} + q_t over T=2048, channels = B*H = 8192 ----------------
// q viewed as [T][8192]; 32 segments of 64. Pass1: in-place local scan + segment carry.
#define NCH 8192
#define SEG 64
#define NSEG 32

__global__ __launch_bounds__(256) void scan_pass1(float* __restrict__ q,
                                                  float* __restrict__ carry,
                                                  const float* __restrict__ beta_arr) {
  int tid = blockIdx.x * 256 + threadIdx.x;  // [0, 32*8192)
  int seg = tid >> 13;
  int ch  = tid & (NCH - 1);
  float beta = beta_arr[ch & 1023];
  float m = 0.f;
  size_t base = (size_t)seg * SEG * NCH + ch;
#pragma unroll 8
  for (int t = 0; t < SEG; t++) {
    float v = q[base + (size_t)t * NCH];
    m = beta * m + v;
    q[base + (size_t)t * NCH] = m;
  }
  carry[tid] = m;
}

// Pass2: sequential scan of segment carries; rewrite carry[s] = incoming value F_{s-1}.
__global__ __launch_bounds__(256) void carry_scan(float* __restrict__ carry,
                                                  const float* __restrict__ beta_arr) {
  int ch = blockIdx.x * 256 + threadIdx.x;  // [0, 8192)
  float beta = beta_arr[ch & 1023];
  float bseg = beta;
#pragma unroll
  for (int i = 0; i < 6; i++) bseg *= bseg;  // beta^64
  float F = 0.f;
#pragma unroll
  for (int s = 0; s < NSEG; s++) {
    float c = carry[(size_t)s * NCH + ch];
    carry[(size_t)s * NCH + ch] = F;
    F = bseg * F + c;
  }
}

// Pass3: m_t = local_m_t + beta^{t+1} * F_in; emit bf16.
__global__ __launch_bounds__(256) void scan_pass3(const float* __restrict__ q,
                                                  const float* __restrict__ carry,
                                                  const float* __restrict__ beta_arr,
                                                  u16* __restrict__ m_bf) {
  int tid = blockIdx.x * 256 + threadIdx.x;
  int seg = tid >> 13;
  int ch  = tid & (NCH - 1);
  float beta = beta_arr[ch & 1023];
  float c = carry[tid];
  size_t base = (size_t)seg * SEG * NCH + ch;
#pragma unroll 8
  for (int t = 0; t < SEG; t++) {
    c *= beta;
    float v = q[base + (size_t)t * NCH] + c;
    m_bf[base + (size_t)t * NCH] = f2bf(v);
  }
}

extern "C" void kernel_launch(void* const* d_in, const int* in_sizes, int n_in,
                              void* d_out, int out_size, void* d_ws, size_t ws_size,
                              hipStream_t stream) {
  const float* x        = (const float*)d_in[0];
  const float* W_q      = (const float*)d_in[1];
  const float* b_q      = (const float*)d_in[2];
  const float* beta_raw = (const float*)d_in[3];
  const float* W_fc     = (const float*)d_in[4];
  const float* b_fc     = (const float*)d_in[5];
  float* out = (float*)d_out;

  const int H = 1024;
  const int M = 2048 * 8;              // T*B = 16384 rows
  const size_t MH = (size_t)M * H;     // 16.7M elements

  char* ws = (char*)d_ws;
  u16* x_bf    = (u16*)ws;  ws += MH * 2;             // 32 MB
  u16* wq_bf   = (u16*)ws;  ws += (size_t)H * H * 2;  // 2 MB
  u16* wfc_bf  = (u16*)ws;  ws += (size_t)H * H * 2;  // 2 MB
  float* beta  = (float*)ws; ws += 4096;
  float* q     = (float*)ws; ws += MH * 4;            // 64 MB (in-place scan)
  u16* m_bf    = (u16*)ws;  ws += MH * 2;             // 32 MB
  float* carry = (float*)ws; ws += (size_t)NSEG * NCH * 4;  // 1 MB

  sigmoid_k<<<4, 256, 0, stream>>>(beta_raw, beta, H);
  cvt_f32_bf16<<<(int)(MH / 4 / 256), 256, 0, stream>>>(x, x_bf, (int)MH);
  cvt_f32_bf16<<<H * H / 4 / 256, 256, 0, stream>>>(W_q, wq_bf, H * H);
  cvt_f32_bf16<<<H * H / 4 / 256, 256, 0, stream>>>(W_fc, wfc_bf, H * H);

  gemm_bt<0><<<dim3(H / 128, M / 128), 256, 0, stream>>>(x_bf, wq_bf, b_q, q, M, H, H);

  scan_pass1<<<NSEG * NCH / 256, 256, 0, stream>>>(q, carry, beta);
  carry_scan<<<NCH / 256, 256, 0, stream>>>(carry, beta);
  scan_pass3<<<NSEG * NCH / 256, 256, 0, stream>>>(q, carry, beta, m_bf);

  gemm_bt<1><<<dim3(H / 128, M / 128), 256, 0, stream>>>(m_bf, wfc_bf, b_fc, out, M, H, H);
}

// Round 2
// 264.297 us; speedup vs baseline: 1.2066x; 1.2066x over previous
//
#include <hip/hip_runtime.h>
#include <stdint.h>

typedef unsigned short u16;
typedef __bf16 bf16x8 __attribute__((ext_vector_type(8)));
typedef float f32x4 __attribute__((ext_vector_type(4)));

__device__ __forceinline__ u16 f2bf(float f) {
  union { float f; uint32_t u; } x; x.f = f;
  uint32_t u = x.u;
  u += 0x7fffu + ((u >> 16) & 1u);   // round-to-nearest-even
  return (u16)(u >> 16);
}
__device__ __forceinline__ float bf2f(uint32_t lo16) {
  union { uint32_t u; float f; } x; x.u = lo16 << 16; return x.f;
}

__device__ __forceinline__ void async_load16(const u16* g, u16* l) {
  __builtin_amdgcn_global_load_lds(
      (const __attribute__((address_space(1))) void*)g,
      (__attribute__((address_space(3))) void*)l,
      16, 0, 0);
}

// ---------------- prep: sigmoid(beta) + both weight converts ----------------
__global__ __launch_bounds__(256) void prep(const float* __restrict__ Wq,
                                            const float* __restrict__ Wfc,
                                            const float* __restrict__ braw,
                                            u16* __restrict__ wqb,
                                            u16* __restrict__ wfcb,
                                            float* __restrict__ beta) {
  int gid = blockIdx.x * 256 + threadIdx.x;
  if (gid < 1024) beta[gid] = 1.0f / (1.0f + expf(-braw[gid]));
  const int HH = 1024 * 1024;
  int i = gid * 4;
  if (i < HH) {
    float4 v = *(const float4*)(Wq + i);
    ushort4 o = {f2bf(v.x), f2bf(v.y), f2bf(v.z), f2bf(v.w)};
    *(ushort4*)(wqb + i) = o;
  } else {
    int j = i - HH;
    float4 v = *(const float4*)(Wfc + j);
    ushort4 o = {f2bf(v.x), f2bf(v.y), f2bf(v.z), f2bf(v.w)};
    *(ushort4*)(wfcb + j) = o;
  }
}

// ---------------- x: fp32 -> bf16, 8 elems/thread ----------------
__global__ __launch_bounds__(256) void cvt_x8(const float* __restrict__ in,
                                              u16* __restrict__ out, int n) {
  int i = (blockIdx.x * 256 + threadIdx.x) * 8;
  if (i < n) {
    float4 a = *(const float4*)(in + i);
    float4 b = *(const float4*)(in + i + 4);
    ushort4 o0 = {f2bf(a.x), f2bf(a.y), f2bf(a.z), f2bf(a.w)};
    ushort4 o1 = {f2bf(b.x), f2bf(b.y), f2bf(b.z), f2bf(b.w)};
    *(ushort4*)(out + i) = o0;
    *(ushort4*)(out + i + 4) = o1;
  }
}

// ---------------- GEMM: C = A (MxK bf16) * B^T (NxK bf16) + bias ----------------
// 128x128 tile, BK=32, 4 waves (2x2), each wave 64x64 via 4x4 mfma_f32_16x16x32_bf16.
// LDS XOR swizzle (bank-conflict-free b128 reads) + XCD-aware tile remap.
template <int RELU, int OUTBF>
__global__ __launch_bounds__(256) void gemm_bt(const u16* __restrict__ A,
                                               const u16* __restrict__ B,
                                               const float* __restrict__ bias,
                                               void* __restrict__ Cout,
                                               int M, int N, int K) {
  __shared__ u16 As[128 * 32];
  __shared__ u16 Bs[128 * 32];

  const int tid  = threadIdx.x;
  const int lane = tid & 63;

  // XCD-aware remap (grid = 1024 = 128 m-tiles x 8 n-tiles; assume xcd = L % 8):
  // XCD c owns m-tiles [16c, 16c+16) x all 8 n-tiles -> per-XCD L2 working set ~3 MB.
  const int L  = blockIdx.x;
  const int xc = L & 7;
  const int k8 = L >> 3;
  const int tile_n = (k8 & 7) * 128;
  const int tile_m = ((xc << 4) | (k8 >> 3)) * 128;

  const int wm = ((tid >> 7) & 1) * 64;
  const int wn = ((tid >> 6) & 1) * 64;

  // staging: lane l of wave w covers LDS row w*16 + l/4, 16B chunk l%4.
  // Global source chunk XOR-swizzled: gc = (l%4) ^ ((l>>3)&3) so that ds_read_b128
  // quad-groups later hit all 8 bank-quads exactly 2x (2-way aliasing = free).
  const int srow = tid >> 2;
  const int scol = (((tid & 3) ^ ((tid >> 3) & 3)) << 3);
  u16* ldsA = &As[(tid >> 6) << 9];
  u16* ldsB = &Bs[(tid >> 6) << 9];

  const u16* gA = A + (size_t)(tile_m + srow) * K + scol;
  const u16* gB = B + (size_t)(tile_n + srow) * K + scol;

  f32x4 acc[4][4];
#pragma unroll
  for (int i = 0; i < 4; i++)
#pragma unroll
    for (int j = 0; j < 4; j++) acc[i][j] = (f32x4){0.f, 0.f, 0.f, 0.f};

  const int lrow = lane & 15;
  const int gcq  = lane >> 4;  // which global 16B k-chunk this lane's fragment wants
  // LDS chunk to read = gcq ^ ((row>>1)&3); row bits 1..2 == lrow bits 1..2 (rows offset by 16s)
  const int ccL8 = (gcq ^ ((lrow >> 1) & 3)) << 3;

  for (int k0 = 0; k0 < K; k0 += 32) {
    __syncthreads();
    async_load16(gA + k0, ldsA);
    async_load16(gA + 64 * (size_t)K + k0, ldsA + 2048);
    async_load16(gB + k0, ldsB);
    async_load16(gB + 64 * (size_t)K + k0, ldsB + 2048);
    __syncthreads();  // drains vmcnt: LDS tiles complete

    bf16x8 a[4], b[4];
#pragma unroll
    for (int i = 0; i < 4; i++)
      a[i] = *(const bf16x8*)&As[(wm + i * 16 + lrow) * 32 + ccL8];
#pragma unroll
    for (int j = 0; j < 4; j++)
      b[j] = *(const bf16x8*)&Bs[(wn + j * 16 + lrow) * 32 + ccL8];
#pragma unroll
    for (int i = 0; i < 4; i++)
#pragma unroll
      for (int j = 0; j < 4; j++)
        acc[i][j] = __builtin_amdgcn_mfma_f32_16x16x32_bf16(a[i], b[j], acc[i][j], 0, 0, 0);
  }

  // C/D layout: col = lane&15, row = (lane>>4)*4 + r  [measured m89/m91]
  const int crow = (lane >> 4) << 2;
  const int ccol = lane & 15;
#pragma unroll
  for (int i = 0; i < 4; i++) {
#pragma unroll
    for (int j = 0; j < 4; j++) {
      const int gm = tile_m + wm + i * 16 + crow;
      const int gn = tile_n + wn + j * 16 + ccol;
      const float bv = bias[gn];
#pragma unroll
      for (int r = 0; r < 4; r++) {
        float v = acc[i][j][r] + bv;
        if (RELU) v = fmaxf(v, 0.f);
        if (OUTBF) ((u16*)Cout)[(size_t)(gm + r) * N + gn] = f2bf(v);
        else       ((float*)Cout)[(size_t)(gm + r) * N + gn] = v;
      }
    }
  }
}

// ---------------- scan: m_t = beta*m_{t-1} + q_t over T=2048, channels = B*H = 8192 ----
// q is bf16 [T][8192]. 64 segments of 32. Decoupled reduce-then-rescan (no fp32 q buffer,
// local m never quantized): pass1 computes segment carries only; pass3 re-scans with the
// carried-in initial value and emits bf16 m. 2 channels/thread (dword-vectorized).
#define NCH 8192
#define SEG 32
#define NSEG 64

__global__ __launch_bounds__(256) void scan_carry(const uint32_t* __restrict__ qb,
                                                  float* __restrict__ carry,
                                                  const float* __restrict__ beta_arr) {
  int tid = blockIdx.x * 256 + threadIdx.x;  // [0, 64*4096)
  int seg = tid >> 12;
  int cp  = tid & 4095;                      // channel pair
  int h0  = (cp * 2) & 1023;
  float b0 = beta_arr[h0], b1 = beta_arr[h0 + 1];
  const uint32_t* p = qb + (size_t)seg * SEG * 4096 + cp;
  float m0 = 0.f, m1 = 0.f;
#pragma unroll 8
  for (int t = 0; t < SEG; t++) {
    uint32_t v = p[(size_t)t * 4096];
    m0 = fmaf(b0, m0, bf2f(v & 0xffffu));
    m1 = fmaf(b1, m1, bf2f(v >> 16));
  }
  *(float2*)&carry[(size_t)seg * NCH + cp * 2] = make_float2(m0, m1);
}

// carry[s][ch] -> rewrite to incoming integrator value F_{s-1}; loads pipelined into regs.
__global__ __launch_bounds__(256) void carry_scan(float* __restrict__ carry,
                                                  const float* __restrict__ beta_arr) {
  int ch = blockIdx.x * 256 + threadIdx.x;  // [0, 8192)
  float beta = beta_arr[ch & 1023];
  float bseg = beta;
#pragma unroll
  for (int i = 0; i < 5; i++) bseg *= bseg;  // beta^32
  float c[NSEG];
#pragma unroll
  for (int s = 0; s < NSEG; s++) c[s] = carry[(size_t)s * NCH + ch];
  float F = 0.f;
#pragma unroll
  for (int s = 0; s < NSEG; s++) { float t = c[s]; c[s] = F; F = fmaf(bseg, F, t); }
#pragma unroll
  for (int s = 0; s < NSEG; s++) carry[(size_t)s * NCH + ch] = c[s];
}

__global__ __launch_bounds__(256) void scan_out(const uint32_t* __restrict__ qb,
                                                const float* __restrict__ carry,
                                                const float* __restrict__ beta_arr,
                                                uint32_t* __restrict__ mb) {
  int tid = blockIdx.x * 256 + threadIdx.x;
  int seg = tid >> 12;
  int cp  = tid & 4095;
  int h0  = (cp * 2) & 1023;
  float b0 = beta_arr[h0], b1 = beta_arr[h0 + 1];
  float2 F = *(const float2*)&carry[(size_t)seg * NCH + cp * 2];
  float m0 = F.x, m1 = F.y;
  const uint32_t* p = qb + (size_t)seg * SEG * 4096 + cp;
  uint32_t* o = mb + (size_t)seg * SEG * 4096 + cp;
#pragma unroll 8
  for (int t = 0; t < SEG; t++) {
    uint32_t v = p[(size_t)t * 4096];
    m0 = fmaf(b0, m0, bf2f(v & 0xffffu));
    m1 = fmaf(b1, m1, bf2f(v >> 16));
    o[(size_t)t * 4096] = (uint32_t)f2bf(m0) | ((uint32_t)f2bf(m1) << 16);
  }
}

extern "C" void kernel_launch(void* const* d_in, const int* in_sizes, int n_in,
                              void* d_out, int out_size, void* d_ws, size_t ws_size,
                              hipStream_t stream) {
  const float* x        = (const float*)d_in[0];
  const float* W_q      = (const float*)d_in[1];
  const float* b_q      = (const float*)d_in[2];
  const float* beta_raw = (const float*)d_in[3];
  const float* W_fc     = (const float*)d_in[4];
  const float* b_fc     = (const float*)d_in[5];

  const int H = 1024;
  const int M = 2048 * 8;              // T*B = 16384 rows
  const size_t MH = (size_t)M * H;     // 16.7M elements

  char* ws = (char*)d_ws;
  u16* x_bf    = (u16*)ws;  ws += MH * 2;                   // 32 MB
  u16* q_bf    = (u16*)ws;  ws += MH * 2;                   // 32 MB
  u16* m_bf    = (u16*)ws;  ws += MH * 2;                   // 32 MB
  u16* wq_bf   = (u16*)ws;  ws += (size_t)H * H * 2;        // 2 MB
  u16* wfc_bf  = (u16*)ws;  ws += (size_t)H * H * 2;        // 2 MB
  float* beta  = (float*)ws; ws += 4096;
  float* carry = (float*)ws; ws += (size_t)NSEG * NCH * 4;  // 2 MB

  prep<<<2048, 256, 0, stream>>>(W_q, W_fc, beta_raw, wq_bf, wfc_bf, beta);
  cvt_x8<<<(int)(MH / 8 / 256), 256, 0, stream>>>(x, x_bf, (int)MH);

  gemm_bt<0, 1><<<1024, 256, 0, stream>>>(x_bf, wq_bf, b_q, q_bf, M, H, H);

  scan_carry<<<NSEG * (NCH / 2) / 256, 256, 0, stream>>>((const uint32_t*)q_bf, carry, beta);
  carry_scan<<<NCH / 256, 256, 0, stream>>>(carry, beta);
  scan_out<<<NSEG * (NCH / 2) / 256, 256, 0, stream>>>((const uint32_t*)q_bf, carry, beta,
                                                       (uint32_t*)m_bf);

  gemm_bt<1, 0><<<1024, 256, 0, stream>>>(m_bf, wfc_bf, b_fc, d_out, M, H, H);
}

// Round 4
// 263.734 us; speedup vs baseline: 1.2092x; 1.0021x over previous
//
#include <hip/hip_runtime.h>
#include <stdint.h>

typedef unsigned short u16;
typedef __bf16 bf16x8 __attribute__((ext_vector_type(8)));
typedef float f32x4 __attribute__((ext_vector_type(4)));

__device__ __forceinline__ u16 f2bf(float f) {
  union { float f; uint32_t u; } x; x.f = f;
  uint32_t u = x.u;
  u += 0x7fffu + ((u >> 16) & 1u);   // round-to-nearest-even
  return (u16)(u >> 16);
}
__device__ __forceinline__ float bf2f(uint32_t lo16) {
  union { uint32_t u; float f; } x; x.u = lo16 << 16; return x.f;
}

__device__ __forceinline__ void async_load16(const u16* g, u16* l) {
  __builtin_amdgcn_global_load_lds(
      (const __attribute__((address_space(1))) void*)g,
      (__attribute__((address_space(3))) void*)l,
      16, 0, 0);
}

// ---------------- prep_all: sigmoid(beta) + weight converts + x convert ----------------
__global__ __launch_bounds__(256) void prep_all(const float* __restrict__ x,
                                                const float* __restrict__ Wq,
                                                const float* __restrict__ Wfc,
                                                const float* __restrict__ braw,
                                                u16* __restrict__ xb,
                                                u16* __restrict__ wqb,
                                                u16* __restrict__ wfcb,
                                                float* __restrict__ beta) {
  int gid = blockIdx.x * 256 + threadIdx.x;
  if (gid < 1024) beta[gid] = 1.0f / (1.0f + expf(-braw[gid]));
  if (gid < 131072) {
    const int HH = 1024 * 1024;
    int i = gid * 16;
    const float* src = (i < HH) ? (Wq + i) : (Wfc + (i - HH));
    u16* dst = (i < HH) ? (wqb + i) : (wfcb + (i - HH));
#pragma unroll
    for (int c = 0; c < 4; c++) {
      float4 v = *(const float4*)(src + c * 4);
      ushort4 o = {f2bf(v.x), f2bf(v.y), f2bf(v.z), f2bf(v.w)};
      *(ushort4*)(dst + c * 4) = o;
    }
  }
  {
    int i = gid * 8;
    float4 a = *(const float4*)(x + i);
    float4 b = *(const float4*)(x + i + 4);
    ushort4 o0 = {f2bf(a.x), f2bf(a.y), f2bf(a.z), f2bf(a.w)};
    ushort4 o1 = {f2bf(b.x), f2bf(b.y), f2bf(b.z), f2bf(b.w)};
    *(ushort4*)(xb + i) = o0;
    *(ushort4*)(xb + i + 4) = o1;
  }
}

// ---------------- GEMM: C = A (MxK bf16) * B^T (NxK bf16) + bias ----------------
// 128x128 tile, BK=32, 4 waves (2x2), each wave 64x64 via 4x4 mfma_f32_16x16x32_bf16.
// Proven round-2 structure (passed full harness incl. graph-replay revalidation),
// plus an EXPLICIT s_waitcnt(all) before the post-staging barrier so the
// global_load_lds drain is contractual, not compiler-shape-dependent.
template <int RELU, int OUTBF>
__global__ __launch_bounds__(256) void gemm_bt(const u16* __restrict__ A,
                                               const u16* __restrict__ B,
                                               const float* __restrict__ bias,
                                               void* __restrict__ Cout,
                                               int M, int N, int K) {
  __shared__ u16 As[128 * 32];
  __shared__ u16 Bs[128 * 32];

  const int tid  = threadIdx.x;
  const int lane = tid & 63;

  // XCD-aware remap (grid = 1024 = 128 m-tiles x 8 n-tiles; xcd = L % 8):
  // XCD c owns m-tiles [16c,16c+16) x all 8 n-tiles -> ~3 MB L2 working set.
  const int L  = blockIdx.x;
  const int xc = L & 7;
  const int k8 = L >> 3;
  const int tile_n = (k8 & 7) * 128;
  const int tile_m = ((xc << 4) | (k8 >> 3)) * 128;

  const int wm = ((tid >> 7) & 1) * 64;
  const int wn = ((tid >> 6) & 1) * 64;

  // staging: lane l of wave w covers LDS row w*16 + l/4, 16B chunk l%4.
  // Global source chunk XOR-swizzled: gc = (l%4) ^ ((l>>3)&3) so ds_read_b128
  // quad-groups later hit all 8 bank-quads exactly 2x (2-way aliasing = free).
  const int srow = tid >> 2;
  const int scol = (((tid & 3) ^ ((tid >> 3) & 3)) << 3);
  u16* ldsA = &As[(tid >> 6) << 9];
  u16* ldsB = &Bs[(tid >> 6) << 9];

  const u16* gA = A + (size_t)(tile_m + srow) * K + scol;
  const u16* gB = B + (size_t)(tile_n + srow) * K + scol;

  f32x4 acc[4][4];
#pragma unroll
  for (int i = 0; i < 4; i++)
#pragma unroll
    for (int j = 0; j < 4; j++) acc[i][j] = (f32x4){0.f, 0.f, 0.f, 0.f};

  const int lrow = lane & 15;
  const int gcq  = lane >> 4;  // which global 16B k-chunk this lane's fragment wants
  const int ccL8 = (gcq ^ ((lrow >> 1) & 3)) << 3;

  for (int k0 = 0; k0 < K; k0 += 32) {
    __syncthreads();
    async_load16(gA + k0, ldsA);
    async_load16(gA + 64 * (size_t)K + k0, ldsA + 2048);
    async_load16(gB + k0, ldsB);
    async_load16(gB + 64 * (size_t)K + k0, ldsB + 2048);
    __builtin_amdgcn_s_waitcnt(0);  // explicit drain: LDS-DMA complete before publish
    __syncthreads();

    bf16x8 a[4], b[4];
#pragma unroll
    for (int i = 0; i < 4; i++)
      a[i] = *(const bf16x8*)&As[(wm + i * 16 + lrow) * 32 + ccL8];
#pragma unroll
    for (int j = 0; j < 4; j++)
      b[j] = *(const bf16x8*)&Bs[(wn + j * 16 + lrow) * 32 + ccL8];
#pragma unroll
    for (int i = 0; i < 4; i++)
#pragma unroll
      for (int j = 0; j < 4; j++)
        acc[i][j] = __builtin_amdgcn_mfma_f32_16x16x32_bf16(a[i], b[j], acc[i][j], 0, 0, 0);
  }

  // C/D layout: col = lane&15, row = (lane>>4)*4 + r  [measured m89/m91]
  const int crow = (lane >> 4) << 2;
  const int ccol = lane & 15;
#pragma unroll
  for (int i = 0; i < 4; i++) {
#pragma unroll
    for (int j = 0; j < 4; j++) {
      const int gm = tile_m + wm + i * 16 + crow;
      const int gn = tile_n + wn + j * 16 + ccol;
      const float bv = bias[gn];
#pragma unroll
      for (int r = 0; r < 4; r++) {
        float v = acc[i][j][r] + bv;
        if (RELU) v = fmaxf(v, 0.f);
        if (OUTBF) ((u16*)Cout)[(size_t)(gm + r) * N + gn] = f2bf(v);
        else       ((float*)Cout)[(size_t)(gm + r) * N + gn] = v;
      }
    }
  }
}

// ---------------- scan: m_t = beta*m_{t-1} + q_t over T=2048, channels = B*H = 8192 ----
// q is bf16 [T][8192]. 64 segments of 32 t-steps. Reduce-then-rescan: pass1 computes
// segment carries (fp32 chains, no double quantization); carry_scan turns them into
// incoming values; pass3 re-scans and emits bf16 m. 4 channels/thread (uint2).
#define NCH 8192
#define SEG 32
#define NSEG 64

__global__ __launch_bounds__(256) void scan_carry(const uint2* __restrict__ qb,
                                                  float* __restrict__ carry,
                                                  const float* __restrict__ beta_arr) {
  int tid = blockIdx.x * 256 + threadIdx.x;  // [0, 64*2048)
  int seg = tid >> 11;
  int cq  = tid & 2047;                      // channel quad
  int h0  = (cq * 4) & 1023;
  float b0 = beta_arr[h0], b1 = beta_arr[h0 + 1], b2 = beta_arr[h0 + 2], b3 = beta_arr[h0 + 3];
  const uint2* p = qb + (size_t)seg * SEG * 2048 + cq;
  float m0 = 0.f, m1 = 0.f, m2 = 0.f, m3 = 0.f;
#pragma unroll 8
  for (int t = 0; t < SEG; t++) {
    uint2 v = p[(size_t)t * 2048];
    m0 = fmaf(b0, m0, bf2f(v.x & 0xffffu));
    m1 = fmaf(b1, m1, bf2f(v.x >> 16));
    m2 = fmaf(b2, m2, bf2f(v.y & 0xffffu));
    m3 = fmaf(b3, m3, bf2f(v.y >> 16));
  }
  *(float4*)&carry[(size_t)seg * NCH + cq * 4] = make_float4(m0, m1, m2, m3);
}

// carry[s][ch] -> rewrite to incoming integrator value F_{s-1}; loads pipelined into regs.
__global__ __launch_bounds__(256) void carry_scan(float* __restrict__ carry,
                                                  const float* __restrict__ beta_arr) {
  int ch = blockIdx.x * 256 + threadIdx.x;  // [0, 8192)
  float beta = beta_arr[ch & 1023];
  float bseg = beta;
#pragma unroll
  for (int i = 0; i < 5; i++) bseg *= bseg;  // beta^32
  float c[NSEG];
#pragma unroll
  for (int s = 0; s < NSEG; s++) c[s] = carry[(size_t)s * NCH + ch];
  float F = 0.f;
#pragma unroll
  for (int s = 0; s < NSEG; s++) { float t = c[s]; c[s] = F; F = fmaf(bseg, F, t); }
#pragma unroll
  for (int s = 0; s < NSEG; s++) carry[(size_t)s * NCH + ch] = c[s];
}

__global__ __launch_bounds__(256) void scan_out(const uint2* __restrict__ qb,
                                                const float* __restrict__ carry,
                                                const float* __restrict__ beta_arr,
                                                uint2* __restrict__ mb) {
  int tid = blockIdx.x * 256 + threadIdx.x;
  int seg = tid >> 11;
  int cq  = tid & 2047;
  int h0  = (cq * 4) & 1023;
  float b0 = beta_arr[h0], b1 = beta_arr[h0 + 1], b2 = beta_arr[h0 + 2], b3 = beta_arr[h0 + 3];
  float4 F = *(const float4*)&carry[(size_t)seg * NCH + cq * 4];
  float m0 = F.x, m1 = F.y, m2 = F.z, m3 = F.w;
  const uint2* p = qb + (size_t)seg * SEG * 2048 + cq;
  uint2* o = mb + (size_t)seg * SEG * 2048 + cq;
#pragma unroll 8
  for (int t = 0; t < SEG; t++) {
    uint2 v = p[(size_t)t * 2048];
    m0 = fmaf(b0, m0, bf2f(v.x & 0xffffu));
    m1 = fmaf(b1, m1, bf2f(v.x >> 16));
    m2 = fmaf(b2, m2, bf2f(v.y & 0xffffu));
    m3 = fmaf(b3, m3, bf2f(v.y >> 16));
    uint2 w;
    w.x = (uint32_t)f2bf(m0) | ((uint32_t)f2bf(m1) << 16);
    w.y = (uint32_t)f2bf(m2) | ((uint32_t)f2bf(m3) << 16);
    o[(size_t)t * 2048] = w;
  }
}

extern "C" void kernel_launch(void* const* d_in, const int* in_sizes, int n_in,
                              void* d_out, int out_size, void* d_ws, size_t ws_size,
                              hipStream_t stream) {
  const float* x        = (const float*)d_in[0];
  const float* W_q      = (const float*)d_in[1];
  const float* b_q      = (const float*)d_in[2];
  const float* beta_raw = (const float*)d_in[3];
  const float* W_fc     = (const float*)d_in[4];
  const float* b_fc     = (const float*)d_in[5];

  const int H = 1024;
  const int M = 2048 * 8;              // T*B = 16384 rows
  const size_t MH = (size_t)M * H;     // 16.7M elements

  char* ws = (char*)d_ws;
  u16* x_bf    = (u16*)ws;  ws += MH * 2;                   // 32 MB
  u16* q_bf    = (u16*)ws;  ws += MH * 2;                   // 32 MB
  u16* m_bf    = (u16*)ws;  ws += MH * 2;                   // 32 MB
  u16* wq_bf   = (u16*)ws;  ws += (size_t)H * H * 2;        // 2 MB
  u16* wfc_bf  = (u16*)ws;  ws += (size_t)H * H * 2;        // 2 MB
  float* beta  = (float*)ws; ws += 4096;
  float* carry = (float*)ws; ws += (size_t)NSEG * NCH * 4;  // 2 MB

  prep_all<<<(int)(MH / 8 / 256), 256, 0, stream>>>(x, W_q, W_fc, beta_raw,
                                                    x_bf, wq_bf, wfc_bf, beta);

  gemm_bt<0, 1><<<1024, 256, 0, stream>>>(x_bf, wq_bf, b_q, q_bf, M, H, H);

  scan_carry<<<NSEG * (NCH / 4) / 256, 256, 0, stream>>>((const uint2*)q_bf, carry, beta);
  carry_scan<<<NCH / 256, 256, 0, stream>>>(carry, beta);
  scan_out<<<NSEG * (NCH / 4) / 256, 256, 0, stream>>>((const uint2*)q_bf, carry, beta,
                                                       (uint2*)m_bf);

  gemm_bt<1, 0><<<1024, 256, 0, stream>>>(m_bf, wfc_bf, b_fc, d_out, M, H, H);
}